// Round 3
// baseline (1166.932 us; speedup 1.0000x reference)
//
#include <hip/hip_runtime.h>

#define NQ   128
#define DIM  256
#define WCN  306      // Ncam*P*L
#define NCAM 6
#define PP   17
#define LV   3
#define TT   4
#define PIX_ELEMS 104448          // 4*128*6*17*2 f32 elements (output 0)
#define OUT_CQ_OFF PIX_ELEMS      // f32-element offset of output-1 region
#define ROW  (2 * DIM)            // 512 f32 per query row: [cq | agg]

__device__ __forceinline__ void calc_tw(const float* ego, float* tw) {
    float e3 = ego[TT - 1];
    #pragma unroll
    for (int t = 0; t < TT; ++t) {
        float d = ego[t] - e3;
        tw[t] = expf(-d * d * 6.0f);   // exp(-td^2/DECAY*3), DECAY=0.5
    }
}

// ---------------------------------------------------------------------------
// Kernel A: copy pixels -> out[0:104448] (float4) and zero the agg slots
// (second 256 f32 of each 512-f32 query row) that serve as the num accumulator.
// grid = 134 blocks x 256 threads.
// ---------------------------------------------------------------------------
__global__ __launch_bounds__(256) void copy_zero_kernel(
    const float* __restrict__ pixels, float* __restrict__ out)
{
    int bid = blockIdx.x, tid = threadIdx.x;
    if (bid < 102) {
        int v = bid * 256 + tid;                    // 26112 float4 = 104448 f32
        ((float4*)out)[v] = ((const float4*)pixels)[v];
    } else {
        int v = (bid - 102) * 256 + tid;            // 8192 threads x float4
        int n  = v >> 6;                            // [0,128)
        int c4 = (v & 63) << 2;                     // [0,256) step 4
        float4* dst = (float4*)(out + OUT_CQ_OFF + n * ROW + DIM + c4);
        *dst = make_float4(0.f, 0.f, 0.f, 0.f);
    }
}

// ---------------------------------------------------------------------------
// Kernel B: gather + weighted accumulate. One block per (g, n) with
// g in [0,18) = (level l, cam); 256 threads = one per channel c.
// Stage: pixels + 17 sigmoid weights + 68 records' bilinear offsets and
// validity-folded corner weights in LDS. Hot loop: 68 x (4 f32 gathers +
// 4 FMA) per thread. atomicAdd f32 into the agg slots of out.
// ---------------------------------------------------------------------------
__global__ __launch_bounds__(256) void gather_kernel(
    const float* __restrict__ cq, const float* __restrict__ pixels,
    const float* __restrict__ ego, const float* __restrict__ Ww,
    const float* __restrict__ bw,
    const float* __restrict__ f0, const float* __restrict__ f1,
    const float* __restrict__ f2, float* __restrict__ out)
{
    int bid = blockIdx.x;
    int n   = bid & (NQ - 1);
    int g   = bid >> 7;            // [0,18)
    int l   = g / NCAM;
    int cam = g - l * NCAM;
    int tid = threadIdx.x;

    __shared__ float cqs[DIM];
    __shared__ float ws[PP];
    __shared__ float pix[TT * PP * 2];
    __shared__ int4   offs4[TT * PP];
    __shared__ float4 wt4[TT * PP];

    cqs[tid] = cq[n * DIM + tid];
    if (tid < TT * PP * 2) {
        int t = tid / (PP * 2);
        int r = tid - t * (PP * 2);
        int p = r >> 1, comp = r & 1;
        pix[tid] = pixels[((((t * NQ + n) * NCAM + cam) * PP + p) << 1) + comp];
    }
    __syncthreads();

    if (tid < PP) {
        int j = cam * (PP * LV) + tid * LV + l;
        float acc = bw[j];
        #pragma unroll 8
        for (int d = 0; d < DIM; ++d) acc += cqs[d] * Ww[d * WCN + j];
        ws[tid] = 1.0f / (1.0f + expf(-acc));
    }
    __syncthreads();

    const int W_ = (l == 0) ? 160 : ((l == 1) ? 80 : 40);
    const int H_ = (l == 0) ? 64  : ((l == 1) ? 32 : 16);
    const int HW = W_ * H_;

    if (tid < TT * PP) {
        int t = tid / PP, p = tid - t * PP;
        float twl[TT]; calc_tw(ego, twl);
        float px0 = pix[(t * PP + p) * 2];
        float px1 = pix[(t * PP + p) * 2 + 1];
        float w = ws[p] * twl[t];
        if (px0 < 0.f) w = 0.f;
        float gx = px0 * 2.f - 1.f, gy = px1 * 2.f - 1.f;
        float ix = (gx + 1.f) * 0.5f * (float)(W_ - 1);
        float iy = (gy + 1.f) * 0.5f * (float)(H_ - 1);
        float x0f = floorf(ix), y0f = floorf(iy);
        float wx1 = ix - x0f, wy1 = iy - y0f;
        float wx0 = 1.f - wx1, wy0 = 1.f - wy1;
        int x0 = (int)x0f, y0 = (int)y0f;
        int x1 = x0 + 1,  y1 = y0 + 1;
        bool vx0 = (x0 >= 0) & (x0 < W_), vx1 = (x1 >= 0) & (x1 < W_);
        bool vy0 = (y0 >= 0) & (y0 < H_), vy1 = (y1 >= 0) & (y1 < H_);
        int cx0 = min(max(x0, 0), W_ - 1), cx1 = min(max(x1, 0), W_ - 1);
        int cy0 = min(max(y0, 0), H_ - 1), cy1 = min(max(y1, 0), H_ - 1);
        offs4[tid] = make_int4(cy0 * W_ + cx0, cy0 * W_ + cx1,
                               cy1 * W_ + cx0, cy1 * W_ + cx1);
        wt4[tid] = make_float4(w * wy0 * wx0 * ((vx0 & vy0) ? 1.f : 0.f),
                               w * wy0 * wx1 * ((vx1 & vy0) ? 1.f : 0.f),
                               w * wy1 * wx0 * ((vx0 & vy1) ? 1.f : 0.f),
                               w * wy1 * wx1 * ((vx1 & vy1) ? 1.f : 0.f));
    }
    __syncthreads();

    const float* fbase = (l == 0) ? f0 : ((l == 1) ? f1 : f2);
    // plane for (cam, t=0, channel=tid); t advances by DIM*HW
    const float* base_c = fbase + (size_t)(cam * TT * DIM + tid) * (size_t)HW;

    float acc = 0.f;
    #pragma unroll
    for (int t = 0; t < TT; ++t) {
        const float* base = base_c + (size_t)t * (size_t)(DIM * HW);
        #pragma unroll 4
        for (int p = 0; p < PP; ++p) {
            int rr = t * PP + p;
            int4 o = offs4[rr];
            float4 w4 = wt4[rr];
            acc += w4.x * base[o.x] + w4.y * base[o.y]
                 + w4.z * base[o.z] + w4.w * base[o.w];
        }
    }
    atomicAdd(&out[OUT_CQ_OFF + n * ROW + DIM + tid], acc);
}

// ---------------------------------------------------------------------------
// Kernel C: epilogue. One block per query n, 512 threads.
// Recompute den (306 sigmoid dots + validity/temporal sum), then
// out_agg[n,c] /= den (in place) and out_cq[n,c] = cq[n,c].
// ---------------------------------------------------------------------------
__global__ __launch_bounds__(512) void epilogue_kernel(
    const float* __restrict__ cq, const float* __restrict__ pixels,
    const float* __restrict__ ego, const float* __restrict__ Ww,
    const float* __restrict__ bw, float* __restrict__ out)
{
    int n = blockIdx.x, tid = threadIdx.x;
    __shared__ float cqs[DIM];
    __shared__ float red[512];
    __shared__ float dsh;

    if (tid < DIM) cqs[tid] = cq[n * DIM + tid];
    __syncthreads();

    float tw[TT]; calc_tw(ego, tw);

    float denj = 0.f;
    if (tid < WCN) {
        int j = tid;
        float acc = bw[j];
        #pragma unroll 8
        for (int d = 0; d < DIM; ++d) acc += cqs[d] * Ww[d * WCN + j];
        float sig = 1.0f / (1.0f + expf(-acc));
        int cam = j / (PP * LV);
        int rem = j - cam * (PP * LV);
        int p   = rem / LV;
        float s = 0.f;
        #pragma unroll
        for (int t = 0; t < TT; ++t) {
            float px0 = pixels[(((t * NQ + n) * NCAM + cam) * PP + p) << 1];
            s += (px0 < 0.f) ? 0.f : tw[t];
        }
        denj = sig * s;
    }
    red[tid] = denj;
    __syncthreads();
    for (int off = 256; off > 0; off >>= 1) {
        if (tid < off) red[tid] += red[tid + off];
        __syncthreads();
    }
    if (tid == 0) dsh = fmaxf(red[0], 1e-6f);
    __syncthreads();

    float den = dsh;
    float* row = out + OUT_CQ_OFF + n * ROW;
    if (tid < DIM) {
        row[tid] = cqs[tid];
        row[DIM + tid] /= den;
    }
}

extern "C" void kernel_launch(void* const* d_in, const int* in_sizes, int n_in,
                              void* d_out, int out_size, void* d_ws, size_t ws_size,
                              hipStream_t stream)
{
    const float* cq     = (const float*)d_in[0];
    const float* pixels = (const float*)d_in[1];
    const float* ego    = (const float*)d_in[2];
    const float* Ww     = (const float*)d_in[3];
    const float* bw     = (const float*)d_in[4];
    const float* f0     = (const float*)d_in[5];
    const float* f1     = (const float*)d_in[6];
    const float* f2     = (const float*)d_in[7];

    float* out = (float*)d_out;

    copy_zero_kernel<<<134, 256, 0, stream>>>(pixels, out);
    gather_kernel<<<18 * NQ, 256, 0, stream>>>(cq, pixels, ego, Ww, bw,
                                               f0, f1, f2, out);
    epilogue_kernel<<<NQ, 512, 0, stream>>>(cq, pixels, ego, Ww, bw, out);
}

// Round 4
// 491.795 us; speedup vs baseline: 2.3728x; 2.3728x over previous
//
#include <hip/hip_runtime.h>

#define NQ   128
#define DIM  256
#define WCN  306      // Ncam*P*L
#define NCAM 6
#define PP   17
#define LV   3
#define TT   4
#define PIX_ELEMS 104448          // 4*128*6*17*2 f32 elements (output 0)
#define OUT_CQ_OFF PIX_ELEMS
#define ROW  (2 * DIM)            // 512 f32 per query row: [cq | agg]

// ---- transposed-feature geometry (channel-last bf16 in d_ws) ----
#define SPAT_L0 245760            // 24 planes * 10240
#define SPAT_L1 61440             // 24 * 2560
#define SPAT_L2 15360             // 24 * 640
#define SPAT_TOTAL (SPAT_L0 + SPAT_L1 + SPAT_L2)   // 322560
#define TF_ELEMS ((size_t)SPAT_TOTAL * 256)        // 82,575,360 bf16
#define TF_BYTES (TF_ELEMS * 2)                    // 165,150,720 B
#define WB_BYTES ((size_t)NQ * WCN * 4)            // 156,672 B
#define WS_NEED  (TF_BYTES + WB_BYTES)

#define SCH 12                    // gather chunks per query
#define RPB 102                   // records per gather block (1224/12)

typedef unsigned short u16;

__device__ __forceinline__ float b2f(u16 u) {
    union { unsigned int i; float f; } v;
    v.i = ((unsigned int)u) << 16;
    return v.f;
}
__device__ __forceinline__ u16 f2b(float f) {
    union { float f; unsigned int i; } v;
    v.f = f;
    unsigned int x = v.i;
    return (u16)((x + 0x7FFFu + ((x >> 16) & 1u)) >> 16);
}
__device__ __forceinline__ void calc_tw(const float* ego, float* tw) {
    float e3 = ego[TT - 1];
    #pragma unroll
    for (int t = 0; t < TT; ++t) {
        float d = ego[t] - e3;
        tw[t] = expf(-d * d * 6.0f);   // exp(-td^2/DECAY*3), DECAY=0.5
    }
}

// ---------------------------------------------------------------------------
// Kernel A: copy pixels -> out[0:104448] and zero the agg slots of out.
// ---------------------------------------------------------------------------
__global__ __launch_bounds__(256) void copy_zero_kernel(
    const float* __restrict__ pixels, float* __restrict__ out)
{
    int bid = blockIdx.x, tid = threadIdx.x;
    if (bid < 102) {
        int v = bid * 256 + tid;
        ((float4*)out)[v] = ((const float4*)pixels)[v];
    } else {
        int v = (bid - 102) * 256 + tid;
        int n  = v >> 6;
        int c4 = (v & 63) << 2;
        float4* dst = (float4*)(out + OUT_CQ_OFF + n * ROW + DIM + c4);
        *dst = make_float4(0.f, 0.f, 0.f, 0.f);
    }
}

// ---------------------------------------------------------------------------
// Kernel P (fast path): wbase[n, j] = sigmoid(cq[n,:].Ww[:,j] + bw[j])
// ---------------------------------------------------------------------------
__global__ __launch_bounds__(320) void prep_wbase_kernel(
    const float* __restrict__ cq, const float* __restrict__ Ww,
    const float* __restrict__ bw, float* __restrict__ wbase)
{
    int n = blockIdx.x, tid = threadIdx.x;
    __shared__ float cqs[DIM];
    if (tid < DIM) cqs[tid] = cq[n * DIM + tid];
    __syncthreads();
    if (tid < WCN) {
        float acc = bw[tid];
        #pragma unroll 8
        for (int d = 0; d < DIM; ++d) acc += cqs[d] * Ww[d * WCN + tid];
        wbase[n * WCN + tid] = 1.0f / (1.0f + expf(-acc));
    }
}

// ---------------------------------------------------------------------------
// Kernel T (fast path): transpose [cam*t][C][H*W] f32 -> [cam*t][H*W][C] bf16.
// 64x64 tiles via LDS. Grid = 15360 (l0) + 3840 (l1) + 960 (l2) = 20160.
// ---------------------------------------------------------------------------
__global__ __launch_bounds__(256) void transpose_kernel(
    const float* __restrict__ f0, const float* __restrict__ f1,
    const float* __restrict__ f2, u16* __restrict__ tf)
{
    __shared__ float lds[64][65];   // [hw_local][c_local], pad 65
    int bid = blockIdx.x, tid = threadIdx.x;
    int plane, ctile, hwtile, HW, spat_base;
    const float* src;
    if (bid < 15360) {
        HW = 10240; src = f0; spat_base = 0;
        plane = bid / 640; int r = bid - plane * 640; ctile = r / 160; hwtile = r - ctile * 160;
    } else if (bid < 19200) {
        int b = bid - 15360; HW = 2560; src = f1; spat_base = SPAT_L0;
        plane = b / 160; int r = b - plane * 160; ctile = r / 40; hwtile = r - ctile * 40;
    } else {
        int b = bid - 19200; HW = 640; src = f2; spat_base = SPAT_L0 + SPAT_L1;
        plane = b / 40; int r = b - plane * 40; ctile = r / 10; hwtile = r - ctile * 10;
    }
    int hw0 = hwtile * 64;
    int c0  = ctile * 64;

    // read: coalesced float4 along hw; thread (cl = tid/16, hl = (tid%16)*4)
    const float* sp = src + ((size_t)plane * 256 + c0) * HW + hw0;
    int cl = tid >> 4;
    int hl = (tid & 15) << 2;
    #pragma unroll
    for (int pass = 0; pass < 4; ++pass) {
        int c = pass * 16 + cl;
        float4 v = *(const float4*)(sp + (size_t)c * HW + hl);
        lds[hl + 0][c] = v.x; lds[hl + 1][c] = v.y;
        lds[hl + 2][c] = v.z; lds[hl + 3][c] = v.w;
    }
    __syncthreads();

    // write: coalesced ushort4 along c; thread (hr = tid/16, c4 = (tid%16)*4)
    int hr = tid >> 4;
    int c4 = (tid & 15) << 2;
    u16* dp = tf + ((size_t)(spat_base + plane * HW + hw0)) * 256 + c0;
    #pragma unroll
    for (int pass = 0; pass < 4; ++pass) {
        int hw = pass * 16 + hr;
        ushort4 o = make_ushort4(f2b(lds[hw][c4 + 0]), f2b(lds[hw][c4 + 1]),
                                 f2b(lds[hw][c4 + 2]), f2b(lds[hw][c4 + 3]));
        *(ushort4*)(dp + (size_t)hw * 256 + c4) = o;
    }
}

// ---------------------------------------------------------------------------
// Kernel G (fast path): coalesced gather from channel-last bf16 features.
// Grid = NQ * SCH blocks; 256 threads = 4 waves. Per block: precompute RPB
// records' corner spatial offsets + validity-folded weights in LDS, then each
// wave processes records i == wave (mod 4): 4 corners x one ushort4 wave-load
// (512 B coalesced) + FMA into acc[4]. Cross-wave LDS reduce, atomicAdd.
// ---------------------------------------------------------------------------
__global__ __launch_bounds__(256) void gather_tr_kernel(
    const float* __restrict__ pixels, const float* __restrict__ ego,
    const float* __restrict__ wbase, const u16* __restrict__ tf,
    float* __restrict__ out)
{
    int bid = blockIdx.x;
    int n = bid / SCH;
    int chunk = bid - n * SCH;
    int tid = threadIdx.x;

    __shared__ int   offs[RPB][4];
    __shared__ float wts[RPB][4];
    __shared__ float red[4][DIM];

    if (tid < RPB) {
        int r = chunk * RPB + tid;
        int t = r / WCN;  int j = r - t * WCN;
        int cam = j / 51; int rem = j - cam * 51;
        int p = rem / 3;  int l = rem - p * 3;
        float e3 = ego[TT - 1];
        float dt = ego[t] - e3;
        float tw = expf(-dt * dt * 6.0f);
        int pidx = (((t * NQ + n) * NCAM + cam) * PP + p) << 1;
        float px0 = pixels[pidx], px1 = pixels[pidx + 1];
        float w = wbase[n * WCN + j] * tw;
        if (px0 < 0.f) w = 0.f;
        int W_ = (l == 0) ? 160 : ((l == 1) ? 80 : 40);
        int H_ = (l == 0) ? 64  : ((l == 1) ? 32 : 16);
        int HW = W_ * H_;
        int sb = (l == 0) ? 0 : ((l == 1) ? SPAT_L0 : (SPAT_L0 + SPAT_L1));
        float ix = px0 * (float)(W_ - 1);     // == (gx+1)/2*(W-1)
        float iy = px1 * (float)(H_ - 1);
        float x0f = floorf(ix), y0f = floorf(iy);
        float wx1 = ix - x0f, wy1 = iy - y0f;
        float wx0 = 1.f - wx1, wy0 = 1.f - wy1;
        int x0 = (int)x0f, y0 = (int)y0f;
        int x1 = x0 + 1,  y1 = y0 + 1;
        bool vx0 = (x0 >= 0) & (x0 < W_), vx1 = (x1 >= 0) & (x1 < W_);
        bool vy0 = (y0 >= 0) & (y0 < H_), vy1 = (y1 >= 0) & (y1 < H_);
        int cx0 = min(max(x0, 0), W_ - 1), cx1 = min(max(x1, 0), W_ - 1);
        int cy0 = min(max(y0, 0), H_ - 1), cy1 = min(max(y1, 0), H_ - 1);
        int base = sb + (cam * TT + t) * HW;
        offs[tid][0] = base + cy0 * W_ + cx0;
        offs[tid][1] = base + cy0 * W_ + cx1;
        offs[tid][2] = base + cy1 * W_ + cx0;
        offs[tid][3] = base + cy1 * W_ + cx1;
        wts[tid][0] = w * wy0 * wx0 * ((vx0 & vy0) ? 1.f : 0.f);
        wts[tid][1] = w * wy0 * wx1 * ((vx1 & vy0) ? 1.f : 0.f);
        wts[tid][2] = w * wy1 * wx0 * ((vx0 & vy1) ? 1.f : 0.f);
        wts[tid][3] = w * wy1 * wx1 * ((vx1 & vy1) ? 1.f : 0.f);
    }
    __syncthreads();

    int wv   = tid >> 6;
    int lane = tid & 63;
    float acc0 = 0.f, acc1 = 0.f, acc2 = 0.f, acc3 = 0.f;
    for (int i = wv; i < RPB; i += 4) {
        #pragma unroll
        for (int q = 0; q < 4; ++q) {
            float wq = wts[i][q];
            ushort4 v = *(const ushort4*)(tf + (size_t)offs[i][q] * 256 + (lane << 2));
            acc0 += wq * b2f(v.x);
            acc1 += wq * b2f(v.y);
            acc2 += wq * b2f(v.z);
            acc3 += wq * b2f(v.w);
        }
    }
    int cb = lane << 2;
    red[wv][cb + 0] = acc0; red[wv][cb + 1] = acc1;
    red[wv][cb + 2] = acc2; red[wv][cb + 3] = acc3;
    __syncthreads();
    if (tid < DIM) {
        float s = red[0][tid] + red[1][tid] + red[2][tid] + red[3][tid];
        atomicAdd(&out[OUT_CQ_OFF + n * ROW + DIM + tid], s);
    }
}

// ---------------------------------------------------------------------------
// Fallback gather (R3, channel-major): one block per (g, n), g = (l, cam).
// ---------------------------------------------------------------------------
__global__ __launch_bounds__(256) void gather_kernel(
    const float* __restrict__ cq, const float* __restrict__ pixels,
    const float* __restrict__ ego, const float* __restrict__ Ww,
    const float* __restrict__ bw,
    const float* __restrict__ f0, const float* __restrict__ f1,
    const float* __restrict__ f2, float* __restrict__ out)
{
    int bid = blockIdx.x;
    int n   = bid & (NQ - 1);
    int g   = bid >> 7;
    int l   = g / NCAM;
    int cam = g - l * NCAM;
    int tid = threadIdx.x;

    __shared__ float cqs[DIM];
    __shared__ float ws[PP];
    __shared__ float pix[TT * PP * 2];
    __shared__ int4   offs4[TT * PP];
    __shared__ float4 wt4[TT * PP];

    cqs[tid] = cq[n * DIM + tid];
    if (tid < TT * PP * 2) {
        int t = tid / (PP * 2);
        int r = tid - t * (PP * 2);
        int p = r >> 1, comp = r & 1;
        pix[tid] = pixels[((((t * NQ + n) * NCAM + cam) * PP + p) << 1) + comp];
    }
    __syncthreads();

    if (tid < PP) {
        int j = cam * (PP * LV) + tid * LV + l;
        float acc = bw[j];
        #pragma unroll 8
        for (int d = 0; d < DIM; ++d) acc += cqs[d] * Ww[d * WCN + j];
        ws[tid] = 1.0f / (1.0f + expf(-acc));
    }
    __syncthreads();

    const int W_ = (l == 0) ? 160 : ((l == 1) ? 80 : 40);
    const int H_ = (l == 0) ? 64  : ((l == 1) ? 32 : 16);
    const int HW = W_ * H_;

    if (tid < TT * PP) {
        int t = tid / PP, p = tid - t * PP;
        float twl[TT]; calc_tw(ego, twl);
        float px0 = pix[(t * PP + p) * 2];
        float px1 = pix[(t * PP + p) * 2 + 1];
        float w = ws[p] * twl[t];
        if (px0 < 0.f) w = 0.f;
        float ix = px0 * (float)(W_ - 1);
        float iy = px1 * (float)(H_ - 1);
        float x0f = floorf(ix), y0f = floorf(iy);
        float wx1 = ix - x0f, wy1 = iy - y0f;
        float wx0 = 1.f - wx1, wy0 = 1.f - wy1;
        int x0 = (int)x0f, y0 = (int)y0f;
        int x1 = x0 + 1,  y1 = y0 + 1;
        bool vx0 = (x0 >= 0) & (x0 < W_), vx1 = (x1 >= 0) & (x1 < W_);
        bool vy0 = (y0 >= 0) & (y0 < H_), vy1 = (y1 >= 0) & (y1 < H_);
        int cx0 = min(max(x0, 0), W_ - 1), cx1 = min(max(x1, 0), W_ - 1);
        int cy0 = min(max(y0, 0), H_ - 1), cy1 = min(max(y1, 0), H_ - 1);
        offs4[tid] = make_int4(cy0 * W_ + cx0, cy0 * W_ + cx1,
                               cy1 * W_ + cx0, cy1 * W_ + cx1);
        wt4[tid] = make_float4(w * wy0 * wx0 * ((vx0 & vy0) ? 1.f : 0.f),
                               w * wy0 * wx1 * ((vx1 & vy0) ? 1.f : 0.f),
                               w * wy1 * wx0 * ((vx0 & vy1) ? 1.f : 0.f),
                               w * wy1 * wx1 * ((vx1 & vy1) ? 1.f : 0.f));
    }
    __syncthreads();

    const float* fbase = (l == 0) ? f0 : ((l == 1) ? f1 : f2);
    const float* base_c = fbase + (size_t)(cam * TT * DIM + tid) * (size_t)HW;

    float acc = 0.f;
    #pragma unroll
    for (int t = 0; t < TT; ++t) {
        const float* base = base_c + (size_t)t * (size_t)(DIM * HW);
        #pragma unroll 4
        for (int p = 0; p < PP; ++p) {
            int rr = t * PP + p;
            int4 o = offs4[rr];
            float4 w4 = wt4[rr];
            acc += w4.x * base[o.x] + w4.y * base[o.y]
                 + w4.z * base[o.z] + w4.w * base[o.w];
        }
    }
    atomicAdd(&out[OUT_CQ_OFF + n * ROW + DIM + tid], acc);
}

// ---------------------------------------------------------------------------
// Kernel C: epilogue — recompute den, divide agg in place, write cq.
// ---------------------------------------------------------------------------
__global__ __launch_bounds__(512) void epilogue_kernel(
    const float* __restrict__ cq, const float* __restrict__ pixels,
    const float* __restrict__ ego, const float* __restrict__ Ww,
    const float* __restrict__ bw, float* __restrict__ out)
{
    int n = blockIdx.x, tid = threadIdx.x;
    __shared__ float cqs[DIM];
    __shared__ float red[512];
    __shared__ float dsh;

    if (tid < DIM) cqs[tid] = cq[n * DIM + tid];
    __syncthreads();

    float tw[TT]; calc_tw(ego, tw);

    float denj = 0.f;
    if (tid < WCN) {
        int j = tid;
        float acc = bw[j];
        #pragma unroll 8
        for (int d = 0; d < DIM; ++d) acc += cqs[d] * Ww[d * WCN + j];
        float sig = 1.0f / (1.0f + expf(-acc));
        int cam = j / (PP * LV);
        int rem = j - cam * (PP * LV);
        int p   = rem / LV;
        float s = 0.f;
        #pragma unroll
        for (int t = 0; t < TT; ++t) {
            float px0 = pixels[(((t * NQ + n) * NCAM + cam) * PP + p) << 1];
            s += (px0 < 0.f) ? 0.f : tw[t];
        }
        denj = sig * s;
    }
    red[tid] = denj;
    __syncthreads();
    for (int off = 256; off > 0; off >>= 1) {
        if (tid < off) red[tid] += red[tid + off];
        __syncthreads();
    }
    if (tid == 0) dsh = fmaxf(red[0], 1e-6f);
    __syncthreads();

    float den = dsh;
    float* row = out + OUT_CQ_OFF + n * ROW;
    if (tid < DIM) {
        row[tid] = cqs[tid];
        row[DIM + tid] /= den;
    }
}

extern "C" void kernel_launch(void* const* d_in, const int* in_sizes, int n_in,
                              void* d_out, int out_size, void* d_ws, size_t ws_size,
                              hipStream_t stream)
{
    const float* cq     = (const float*)d_in[0];
    const float* pixels = (const float*)d_in[1];
    const float* ego    = (const float*)d_in[2];
    const float* Ww     = (const float*)d_in[3];
    const float* bw     = (const float*)d_in[4];
    const float* f0     = (const float*)d_in[5];
    const float* f1     = (const float*)d_in[6];
    const float* f2     = (const float*)d_in[7];

    float* out = (float*)d_out;
    bool fast = (d_ws != nullptr) && (ws_size >= WS_NEED);

    copy_zero_kernel<<<134, 256, 0, stream>>>(pixels, out);

    if (fast) {
        u16*   tf    = (u16*)d_ws;
        float* wbase = (float*)((char*)d_ws + TF_BYTES);
        prep_wbase_kernel<<<NQ, 320, 0, stream>>>(cq, Ww, bw, wbase);
        transpose_kernel<<<20160, 256, 0, stream>>>(f0, f1, f2, tf);
        gather_tr_kernel<<<NQ * SCH, 256, 0, stream>>>(pixels, ego, wbase, tf, out);
    } else {
        gather_kernel<<<18 * NQ, 256, 0, stream>>>(cq, pixels, ego, Ww, bw,
                                                   f0, f1, f2, out);
    }

    epilogue_kernel<<<NQ, 512, 0, stream>>>(cq, pixels, ego, Ww, bw, out);
}